// Round 2
// baseline (90.522 us; speedup 1.0000x reference)
//
#include <hip/hip_runtime.h>
#include <hip/hip_bf16.h>

typedef __bf16 bf16x8 __attribute__((ext_vector_type(8)));
typedef float  f32x4  __attribute__((ext_vector_type(4)));

#define C_IN   128
#define HW     3136
#define IMG_W  56
#define IMG_H  56
#define RPB    2                 // output rows per block
#define NRP    28                // 56/2 row-chunks per image
#define NIMG   32
#define NBLK   (NIMG*NRP)        // 896
#define PITCH  272               // bytes per staged position (128 bf16 data + 8 pad)
#define LDS_BYTES (4*64*PITCH)   // 69632
#define WELEMS (9*128*128)

// ---- weight fp32 -> bf16 pre-pass ----
__global__ __launch_bounds__(256) void wcvt_kernel(const float* __restrict__ w,
                                                   __bf16* __restrict__ wb, int n) {
    int i = blockIdx.x * 256 + threadIdx.x;
    if (i < n) wb[i] = (__bf16)w[i];
}

template<bool WS>
__device__ __forceinline__ bf16x8 load_a(const void* wp, int elem_off) {
    if constexpr (WS) {
        return *(const bf16x8*)((const __bf16*)wp + elem_off);
    } else {
        const float* p = (const float*)wp + elem_off;
        float4 lo = *(const float4*)p;
        float4 hi = *(const float4*)(p + 4);
        bf16x8 r;
        r[0]=(__bf16)lo.x; r[1]=(__bf16)lo.y; r[2]=(__bf16)lo.z; r[3]=(__bf16)lo.w;
        r[4]=(__bf16)hi.x; r[5]=(__bf16)hi.y; r[6]=(__bf16)hi.z; r[7]=(__bf16)hi.w;
        return r;
    }
}

// One wave: 64 oc x (NPF*16) positions. No masking -- zero borders in LDS.
template<int NPF, bool WS>
__device__ __forceinline__ void compute_store(const unsigned char* xs, const void* wp,
                                              float* on, int oc0, int pf0, int r0, int lane) {
    const int l15 = lane & 15, lq = lane >> 4;

    int spb[NPF];
    #pragma unroll
    for (int k = 0; k < NPF; ++k) {
        int p = (pf0 + k) * 16 + l15;              // 0..111 block-local pos
        int r = p / 56, w = p - r * 56;
        spb[k] = ((r + 1) * 64 + (w + 1)) * PITCH + lq * 16;
    }

    f32x4 acc[4][NPF];
    #pragma unroll
    for (int f = 0; f < 4; ++f)
        #pragma unroll
        for (int k = 0; k < NPF; ++k) acc[f][k] = (f32x4){0.f, 0.f, 0.f, 0.f};

    #pragma unroll 3
    for (int tap = 0; tap < 9; ++tap) {
        const int offb  = ((tap / 3) * 64 + (tap % 3) - 65) * PITCH;   // (dh*64+dw)*PITCH
        const int wbase = tap * 16384 + oc0 * 128 + l15 * 128 + lq * 8;
        #pragma unroll
        for (int c = 0; c < 4; ++c) {              // 32 channels per step
            bf16x8 a[4];
            #pragma unroll
            for (int f = 0; f < 4; ++f) a[f] = load_a<WS>(wp, wbase + f * 2048 + c * 32);
            #pragma unroll
            for (int k = 0; k < NPF; ++k) {
                bf16x8 b = *(const bf16x8*)(xs + spb[k] + offb + c * 64);
                #pragma unroll
                for (int f = 0; f < 4; ++f)
                    acc[f][k] = __builtin_amdgcn_mfma_f32_16x16x32_bf16(a[f], b, acc[f][k], 0, 0, 0);
            }
        }
    }

    #pragma unroll
    for (int f = 0; f < 4; ++f)
        #pragma unroll
        for (int k = 0; k < NPF; ++k) {
            int pos = r0 * 56 + (pf0 + k) * 16 + l15;
            int oc  = oc0 + f * 16 + lq * 4;
            #pragma unroll
            for (int rr = 0; rr < 4; ++rr)
                on[(size_t)(oc + rr) * HW + pos] = acc[f][k][rr];
        }
}

template<bool WS>
__global__ __launch_bounds__(256, 2) void conv_kernel(const float* __restrict__ x,
                                                      const void* __restrict__ wp,
                                                      float* __restrict__ out) {
    __shared__ __align__(16) unsigned char xs[LDS_BYTES];

    const int tid  = threadIdx.x;
    const int lane = tid & 63;
    const int wv   = tid >> 6;

    const int bid = blockIdx.x;
    const int swz = (bid & 7) * (NBLK / 8) + (bid >> 3);   // XCD-contiguous (4 images/XCD)
    const int n   = swz / NRP;
    const int rp  = swz - n * NRP;
    const int r0  = rp * RPB;

    // ---- stage 4 rows x 64 cols x 128 ch, fp32->bf16, zero borders ----
    {
        const float* xn = x + (size_t)n * C_IN * HW;
        const int rs = wv;                         // one staged row per wave
        const int ar = r0 - 1 + rs;                // absolute image row
        const int wi = lane - 1;                   // absolute image col
        const bool v = (ar >= 0) & (ar < IMG_H) & (wi >= 0) & (wi < IMG_W);
        const int gc = min(max(ar, 0), IMG_H - 1) * IMG_W + min(max(wi, 0), IMG_W - 1);
        unsigned char* dst = (unsigned char*)xs + (rs * 64 + lane) * PITCH;
        #pragma unroll
        for (int cg = 0; cg < 16; ++cg) {
            bf16x8 pk;
            #pragma unroll
            for (int j = 0; j < 8; ++j) {
                float f = xn[(size_t)(cg * 8 + j) * HW + gc];
                pk[j] = (__bf16)(v ? f : 0.f);
            }
            *(bf16x8*)(dst + cg * 16) = pk;
        }
    }
    __syncthreads();

    const int oc0 = (wv & 1) * 64;
    float* on = out + (size_t)n * 128 * HW;
    if ((wv >> 1) == 0) compute_store<4, WS>(xs, wp, on, oc0, 0, r0, lane);
    else                compute_store<3, WS>(xs, wp, on, oc0, 4, r0, lane);
}

extern "C" void kernel_launch(void* const* d_in, const int* in_sizes, int n_in,
                              void* d_out, int out_size, void* d_ws, size_t ws_size,
                              hipStream_t stream) {
    const float* x = (const float*)d_in[0];
    const float* w = (const float*)d_in[1];
    float* out = (float*)d_out;

    if (ws_size >= (size_t)WELEMS * 2) {
        __bf16* wb = (__bf16*)d_ws;
        wcvt_kernel<<<(WELEMS + 255) / 256, 256, 0, stream>>>(w, wb, WELEMS);
        conv_kernel<true><<<NBLK, 256, 0, stream>>>(x, (const void*)wb, out);
    } else {
        conv_kernel<false><<<NBLK, 256, 0, stream>>>(x, (const void*)w, out);
    }
}